// Round 9
// baseline (80.603 us; speedup 1.0000x reference)
//
#include <hip/hip_runtime.h>
#include <math.h>

#pragma clang fp contract(off)

#define LL 4096
#define FF 128
#define NB 32
#define BASE 16
#define NBLK 256            // 16-tiles per column
#define NOB 16

__device__ __forceinline__ float sani(float v) {
    return (fabsf(v) <= 3.0e38f) ? v : 0.0f;
}

// ---------- K1: per-tile sequential totals (level-0 tails) ----------
__global__ __launch_bounds__(256) void k_tiles(const float* __restrict__ x,
                                               float2* __restrict__ T0) {
    __shared__ float xs[32 * FF];        // 16 KB
    const int bid  = blockIdx.x;         // 32 b x 128 tile-pairs
    const int pair = bid & 127;
    const int b    = bid >> 7;
    const int tid  = (int)threadIdx.x;
    const float* xb = x + ((size_t)b * LL + (size_t)pair * 32) * FF;
    for (int i = tid; i < 32 * FF; i += 256) xs[i] = sani(xb[i]);
    __syncthreads();
    const int f = tid & 127, t = tid >> 7;       // t in 0..1
    const int blk = pair * 2 + t;
    float cs, cs2;
    {
        const float v = xs[(t * 16) * FF + f];
        cs = v; cs2 = __fmul_rn(v, v);
    }
#pragma unroll
    for (int u = 1; u < 16; ++u) {
        const float v = xs[(t * 16 + u) * FF + f];
        cs  = __fadd_rn(cs,  v);
        cs2 = __fadd_rn(cs2, __fmul_rn(v, v));
    }
    T0[((size_t)b * NBLK + blk) * FF + f] = make_float2(cs, cs2);
}

// ---------- K2: per-column levels 1+2 scan -> per-tile prefix P ----------
__global__ __launch_bounds__(64) void k_prefix(const float2* __restrict__ T0,
                                               float2* __restrict__ P) {
    const int bid = blockIdx.x;          // 64 = 32 b x 2 f-halves
    const int fh = bid & 1, b = bid >> 1;
    const int f  = fh * 64 + (int)threadIdx.x;
    const float2* t0c = T0 + (size_t)b * NBLK * FF + f;
    float2*       pc  = P  + (size_t)b * NBLK * FF + f;
    pc[0] = make_float2(0.0f, 0.0f);
    float S2x = 0.0f, S2y = 0.0f;        // S2 over completed groups
    for (int g = 0; g < NOB; ++g) {
        float s1x = 0.0f, s1y = 0.0f;
#pragma unroll
        for (int i = 0; i < 16; ++i) {
            const int B = g * 16 + i;
            const float2 t = t0c[(size_t)B * FF];
            if (i == 0) { s1x = t.x; s1y = t.y; }
            else        { s1x = __fadd_rn(s1x, t.x); s1y = __fadd_rn(s1y, t.y); }
            if (B < NBLK - 1) {
                float px = s1x, py = s1y;
                if (g > 0) { px = __fadd_rn(s1x, S2x); py = __fadd_rn(s1y, S2y); }
                pc[(size_t)(B + 1) * FF] = make_float2(px, py);
            }
        }
        if (g == 0) { S2x = s1x; S2y = s1y; }
        else        { S2x = __fadd_rn(S2x, s1x); S2y = __fadd_rn(S2y, s1y); }
    }
}

// ---------- K3: all-register window kernel ----------
// Thread owns tile (16 outputs, one f). Re-derives V (realization-locked RN
// chain + per-element P add) for tiles tile-1, tile, tile+1 into registers
// Vx/Vy[48]; all window accesses are compile-time positions u+5..u+25.
template<bool GUARD>
__global__ __launch_bounds__(256) void k_win_reg(const float* __restrict__ x,
                                                 const float* __restrict__ w,
                                                 const float2* __restrict__ P,
                                                 float* __restrict__ out,
                                                 int pair_base, int pair_stride) {
    const int pair = pair_base + (int)blockIdx.x * pair_stride;
    const int b    = (int)blockIdx.y;
    const int tid  = (int)threadIdx.x;
    const int f    = tid & 127;
    const int tile = pair * 2 + (tid >> 7);
    const int lbase = tile * 16;
    const int base  = lbase - 16;        // global l of register position 0

    // prefixes for the three segments (0 outside range; guarded blocks only)
    const float2* Pb = P + (size_t)b * NBLK * FF + f;
    float2 Pm = make_float2(0.0f, 0.0f), Pl = make_float2(0.0f, 0.0f);
    if (!GUARD || tile >= 1)        Pm = Pb[(size_t)(tile - 1) * FF];
    const float2 Pc = Pb[(size_t)tile * FF];
    if (!GUARD || tile <= NBLK - 2) Pl = Pb[(size_t)(tile + 1) * FF];

    const float* xb = x + ((size_t)b * LL + lbase) * FF + f;  // position 16

    float Vx[48], Vy[48], xr[16];

#define SEG(OFF, PP)                                                          \
    {                                                                         \
        float cs = 0.0f, cs2 = 0.0f;                                          \
        _Pragma("unroll")                                                     \
        for (int u = 0; u < 16; ++u) {                                        \
            const int p = (OFF) + u;                                          \
            float v = 0.0f;                                                   \
            if (!GUARD || ((unsigned)(base + p) < (unsigned)LL))              \
                v = sani(xb[(size_t)(p - 16) * FF]);                          \
            if ((OFF) == 16) xr[u] = v;                                       \
            if (u == 0) { cs = v; cs2 = __fmul_rn(v, v); }                    \
            else { cs = __fadd_rn(cs, v);                                     \
                   cs2 = __fadd_rn(cs2, __fmul_rn(v, v)); }                   \
            Vx[p] = __fadd_rn(cs,  (PP).x);                                   \
            Vy[p] = __fadd_rn(cs2, (PP).y);                                   \
        }                                                                     \
    }
    SEG(0, Pm)
    SEG(16, Pc)
    SEG(32, Pl)
#undef SEG

    // softmax over 3 weights (uniform)
    const float w0 = w[0], w1 = w[1], w2 = w[2];
    const float mx = fmaxf(w0, fmaxf(w1, w2));
    const float e0 = expf(w0 - mx), e1 = expf(w1 - mx), e2 = expf(w2 - mx);
    const float s  = e0 + e1 + e2;
    const float ws0 = e0 / s, ws1 = e1 / s, ws2 = e2 / s;

    float* ob = out + ((size_t)b * LL + lbase) * FF + f;

#pragma unroll
    for (int u = 0; u < 16; ++u) {
        const int l = lbase + u;
        const float xc = xr[u];
        const float g5  = (l >= 2  && l <= LL - 3)  ? ws0 : 0.0f;
        const float g10 = (l >= 5  && l <= LL - 5)  ? ws1 : 0.0f;
        const float g20 = (l >= 10 && l <= LL - 10) ? ws2 : 0.0f;
        float o;
        {   // w=5:  cs_arr[l+3] -> pos u+18, cs_arr[l-2] -> pos u+13
            const float mean = (Vx[u + 18] - Vx[u + 13]) * 0.2f;
            const float m2   = (Vy[u + 18] - Vy[u + 13]) * 0.2f;
            const float var  = fmaxf(m2 - mean * mean, 0.0f);
            o = g5 * ((xc - mean) * rsqrtf(var + 1e-5f));
        }
        {   // w=10: pos u+20 / u+10
            const float mean = (Vx[u + 20] - Vx[u + 10]) * 0.1f;
            const float m2   = (Vy[u + 20] - Vy[u + 10]) * 0.1f;
            const float var  = fmaxf(m2 - mean * mean, 0.0f);
            o += g10 * ((xc - mean) * rsqrtf(var + 1e-5f));
        }
        {   // w=20: pos u+25 / u+5
            const float mean = (Vx[u + 25] - Vx[u + 5]) * 0.05f;
            const float m2   = (Vy[u + 25] - Vy[u + 5]) * 0.05f;
            const float var  = fmaxf(m2 - mean * mean, 0.0f);
            o += g20 * ((xc - mean) * rsqrtf(var + 1e-5f));
        }
        ob[(size_t)u * FF] = o;
    }
}

// ---------- fallback: verified single-kernel r6 (if ws too small) ----------
__global__ __launch_bounds__(256) void fan_blocked(const float* __restrict__ x,
                                                   const float* __restrict__ w,
                                                   float* __restrict__ out) {
    __shared__ float2 V[LL];
    __shared__ float2 T0s[NBLK];
    __shared__ float2 T1[NOB];
    __shared__ float2 S2[NOB];
    const int col = blockIdx.x;
    const int f   = col & (FF - 1);
    const int b   = col >> 7;
    const int tid = (int)threadIdx.x;
    const float* xcol = x   + (size_t)b * LL * FF + f;
    float*       ocol = out + (size_t)b * LL * FF + f;
    for (int l = tid; l < LL; l += 256) {
        const float v = sani(xcol[(size_t)l * FF]);
        V[l] = make_float2(v, __fmul_rn(v, v));
    }
    __syncthreads();
    {
        const int bse = tid * BASE;
        float cs = V[bse].x, cs2 = V[bse].y;
        for (int u = 1; u < BASE; ++u) {
            const float2 e = V[bse + u];
            cs = __fadd_rn(cs, e.x); cs2 = __fadd_rn(cs2, e.y);
            V[bse + u] = make_float2(cs, cs2);
        }
        T0s[tid] = make_float2(cs, cs2);
    }
    __syncthreads();
    if (tid < NOB) {
        const int bse = tid * BASE;
        float cs = T0s[bse].x, cs2 = T0s[bse].y;
        for (int u = 1; u < BASE; ++u) {
            const float2 e = T0s[bse + u];
            cs = __fadd_rn(cs, e.x); cs2 = __fadd_rn(cs2, e.y);
            T0s[bse + u] = make_float2(cs, cs2);
        }
        T1[tid] = make_float2(cs, cs2);
    }
    __syncthreads();
    if (tid == 0) {
        float cs = T1[0].x, cs2 = T1[0].y;
        S2[0] = T1[0];
        for (int o = 1; o < NOB; ++o) {
            cs = __fadd_rn(cs, T1[o].x); cs2 = __fadd_rn(cs2, T1[o].y);
            S2[o] = make_float2(cs, cs2);
        }
    }
    __syncthreads();
    {
        const int blk = tid;
        if (blk > 0) {
            const int B = blk - 1, ob2 = B >> 4;
            float2 Pp = T0s[B];
            if (ob2 > 0) {
                const float2 s2 = S2[ob2 - 1];
                Pp = make_float2(__fadd_rn(Pp.x, s2.x), __fadd_rn(Pp.y, s2.y));
            }
            const int bse = blk * BASE;
            for (int u = 0; u < BASE; ++u) {
                const float2 sv = V[bse + u];
                V[bse + u] = make_float2(__fadd_rn(sv.x, Pp.x), __fadd_rn(sv.y, Pp.y));
            }
        }
    }
    __syncthreads();
    const float w0 = w[0], w1 = w[1], w2 = w[2];
    const float mx = fmaxf(w0, fmaxf(w1, w2));
    const float e0 = expf(w0 - mx), e1 = expf(w1 - mx), e2 = expf(w2 - mx);
    const float s  = e0 + e1 + e2;
    const float ws0 = e0 / s, ws1 = e1 / s, ws2 = e2 / s;
    auto PV = [&](int j) -> float2 {
        if (j <= 0) return make_float2(0.0f, 0.0f);
        int idx = j - 1; if (idx > LL - 1) idx = LL - 1;
        return V[idx];
    };
    for (int l = tid; l < LL; l += 256) {
        const float xc = sani(xcol[(size_t)l * FF]);
        const float2 A5 = PV(l + 3), B5 = PV(l - 2);
        const float2 A10 = PV(l + 5), B10 = PV(l - 5);
        const float2 A20 = PV(l + 10), B20 = PV(l - 10);
        const float g5  = (l >= 2  && l <= LL - 3)  ? ws0 : 0.0f;
        const float g10 = (l >= 5  && l <= LL - 5)  ? ws1 : 0.0f;
        const float g20 = (l >= 10 && l <= LL - 10) ? ws2 : 0.0f;
        float o;
        {
            const float mean = (A5.x - B5.x) * 0.2f;
            const float m2   = (A5.y - B5.y) * 0.2f;
            const float var  = fmaxf(m2 - mean * mean, 0.0f);
            o = g5 * ((xc - mean) * rsqrtf(var + 1e-5f));
        }
        {
            const float mean = (A10.x - B10.x) * 0.1f;
            const float m2   = (A10.y - B10.y) * 0.1f;
            const float var  = fmaxf(m2 - mean * mean, 0.0f);
            o += g10 * ((xc - mean) * rsqrtf(var + 1e-5f));
        }
        {
            const float mean = (A20.x - B20.x) * 0.05f;
            const float m2   = (A20.y - B20.y) * 0.05f;
            const float var  = fmaxf(m2 - mean * mean, 0.0f);
            o += g20 * ((xc - mean) * rsqrtf(var + 1e-5f));
        }
        ocol[(size_t)l * FF] = o;
    }
}

extern "C" void kernel_launch(void* const* d_in, const int* in_sizes, int n_in,
                              void* d_out, int out_size, void* d_ws, size_t ws_size,
                              hipStream_t stream) {
    const float* x = (const float*)d_in[0];
    const float* w = (const float*)d_in[1];
    float* out     = (float*)d_out;

    const size_t t0_bytes = (size_t)NB * NBLK * FF * sizeof(float2);   // 8 MiB
    if (ws_size >= 2 * t0_bytes) {
        float2* T0 = (float2*)d_ws;
        float2* P  = (float2*)((char*)d_ws + t0_bytes);
        k_tiles <<<dim3(NB * 128), dim3(256), 0, stream>>>(x, T0);
        k_prefix<<<dim3(NB * 2),   dim3(64),  0, stream>>>(T0, P);
        // interior pairs 1..126 (tiles 2..253): no guards
        k_win_reg<false><<<dim3(126, NB), dim3(256), 0, stream>>>(x, w, P, out, 1, 1);
        // edge pairs 0 and 127 (tiles 0,1,254,255): guarded
        k_win_reg<true ><<<dim3(2,   NB), dim3(256), 0, stream>>>(x, w, P, out, 0, 127);
    } else {
        fan_blocked<<<dim3(NB * FF), dim3(256), 0, stream>>>(x, w, out);
    }
}

// Round 10
// 64.705 us; speedup vs baseline: 1.2457x; 1.2457x over previous
//
#include <hip/hip_runtime.h>
#include <math.h>

#pragma clang fp contract(off)

#define LL 4096
#define FF 128
#define NB 32
#define BASE 16
#define NBLK 256
#define NOB 16

__device__ __forceinline__ float sani(float v) {
    return (fabsf(v) <= 3.0e38f) ? v : 0.0f;
}

// ---------- K1: per-tile sequential totals (direct, coalesced) ----------
__global__ __launch_bounds__(256) void k_tiles(const float* __restrict__ x,
                                               float2* __restrict__ T0) {
    const int pair = (int)blockIdx.x;     // 0..127
    const int b    = (int)blockIdx.y;     // 0..31
    const int tid  = (int)threadIdx.x;
    const int f    = tid & 127;
    const int tile = pair * 2 + (tid >> 7);
    const float* xb = x + ((size_t)b * LL + (size_t)tile * 16) * FF + f;
    float cs, cs2;
    {
        const float v = sani(xb[0]);
        cs = v; cs2 = __fmul_rn(v, v);
    }
#pragma unroll
    for (int u = 1; u < 16; ++u) {
        const float v = sani(xb[(size_t)u * FF]);
        cs  = __fadd_rn(cs,  v);
        cs2 = __fadd_rn(cs2, __fmul_rn(v, v));
    }
    T0[((size_t)b * NBLK + tile) * FF + f] = make_float2(cs, cs2);
}

// ---------- K2a: in-place s1 (RN scan within each 16-group of T0) ----------
__global__ __launch_bounds__(128) void k_pref_a(float2* __restrict__ T0) {
    const int g = (int)blockIdx.x & 15;
    const int b = (int)blockIdx.x >> 4;   // grid 512 = 32*16
    const int f = (int)threadIdx.x;
    float2* p = T0 + ((size_t)b * NBLK + (size_t)g * 16) * FF + f;
    float2 t[16];
#pragma unroll
    for (int i = 0; i < 16; ++i) t[i] = p[(size_t)i * FF];
    float sx = t[0].x, sy = t[0].y;       // s1[0] = T0[0], already in place
#pragma unroll
    for (int i = 1; i < 16; ++i) {
        sx = __fadd_rn(sx, t[i].x);
        sy = __fadd_rn(sy, t[i].y);
        p[(size_t)i * FF] = make_float2(sx, sy);
    }
}

// ---------- K2b: S2 = RN scan of group totals (= s1 slot 15 of each group) ----------
__global__ __launch_bounds__(128) void k_pref_b(const float2* __restrict__ S1,
                                                float2* __restrict__ S2) {
    const int b = (int)blockIdx.x;        // 32
    const int f = (int)threadIdx.x;
    const float2* base = S1 + (size_t)b * NBLK * FF + f;
    float2* s2 = S2 + (size_t)b * NOB * FF + f;
    float2 t = base[(size_t)15 * FF];
    float sx = t.x, sy = t.y;
    s2[0] = t;
    for (int g = 1; g < NOB; ++g) {
        const float2 tg = base[(size_t)(g * 16 + 15) * FF];
        sx = __fadd_rn(sx, tg.x);
        sy = __fadd_rn(sy, tg.y);
        s2[(size_t)g * FF] = make_float2(sx, sy);
    }
}

// ---------- K3: LDS-staged x, register V chains, window phase ----------
// Block = (pair, b): 2 tiles x 128 f. LDS holds x rows [pair*32-16, pair*32+48).
__global__ __launch_bounds__(256) void k_win2(const float* __restrict__ x,
                                              const float* __restrict__ w,
                                              const float2* __restrict__ S1,
                                              const float2* __restrict__ S2,
                                              float* __restrict__ out) {
    __shared__ float xs[64 * FF];         // 32 KB
    const int pair = (int)blockIdx.x;     // 0..127
    const int b    = (int)blockIdx.y;     // 0..31
    const int tid  = (int)threadIdx.x;
    const int l0   = pair * 32 - 16;      // global row of LDS row 0

    // stage 64 rows x 128 f, coalesced float4; row-clamp handles both edges
    const float* xb = x + (size_t)b * LL * FF;
#pragma unroll
    for (int it = 0; it < 8; ++it) {
        const int idx = it * 1024 + tid * 4;
        const int row = idx >> 7;
        const int col = idx & 127;
        const int g   = l0 + row;
        float4 v = make_float4(0.0f, 0.0f, 0.0f, 0.0f);
        if ((unsigned)g < (unsigned)LL)
            v = *reinterpret_cast<const float4*>(xb + (size_t)g * FF + col);
        v.x = sani(v.x); v.y = sani(v.y); v.z = sani(v.z); v.w = sani(v.w);
        *reinterpret_cast<float4*>(&xs[row * FF + col]) = v;
    }
    __syncthreads();

    const int t    = tid >> 7;
    const int f    = tid & 127;
    const int tile = pair * 2 + t;
    const int rb   = t * 16;              // LDS row of register position 0

    // compose P (exact r6 op order): scan1[B] = s1[B] (+ RN add of S2[gB-1])
    auto PB = [&](int B) -> float2 {
        if (B < 0) return make_float2(0.0f, 0.0f);
        float2 p = S1[((size_t)b * NBLK + B) * FF + f];
        const int g = B >> 4;
        if (g > 0) {
            const float2 s2 = S2[((size_t)b * NOB + (g - 1)) * FF + f];
            p.x = __fadd_rn(p.x, s2.x);
            p.y = __fadd_rn(p.y, s2.y);
        }
        return p;
    };
    const float2 PA  = PB(tile - 2);      // prefix of segment tile-1
    const float2 PBm = PB(tile - 1);      // prefix of segment tile
    const float2 PC  = PB(tile);          // prefix of segment tile+1

    float Vx[41], Vy[41], xr[16];

#define SEG(P0, N, PP, SAVE)                                         \
    {                                                                \
        float cs = 0.0f, cs2 = 0.0f;                                 \
        _Pragma("unroll")                                            \
        for (int u = 0; u < (N); ++u) {                              \
            const float v = xs[(rb + (P0) + u) * FF + f];            \
            if (SAVE) xr[u] = v;                                     \
            if (u == 0) { cs = v; cs2 = __fmul_rn(v, v); }           \
            else { cs = __fadd_rn(cs, v);                            \
                   cs2 = __fadd_rn(cs2, __fmul_rn(v, v)); }          \
            Vx[(P0) + u] = __fadd_rn(cs,  (PP).x);                   \
            Vy[(P0) + u] = __fadd_rn(cs2, (PP).y);                   \
        }                                                            \
    }
    SEG(0,  16, PA,  false)
    SEG(16, 16, PBm, true)
    SEG(32, 9,  PC,  false)
#undef SEG

    // softmax over 3 weights (uniform)
    const float w0 = w[0], w1 = w[1], w2 = w[2];
    const float mx = fmaxf(w0, fmaxf(w1, w2));
    const float e0 = expf(w0 - mx), e1 = expf(w1 - mx), e2 = expf(w2 - mx);
    const float s  = e0 + e1 + e2;
    const float ws0 = e0 / s, ws1 = e1 / s, ws2 = e2 / s;

    float* ob = out + ((size_t)b * LL + (size_t)tile * 16) * FF + f;

#pragma unroll
    for (int u = 0; u < 16; ++u) {
        const int l = tile * 16 + u;
        const float xc = xr[u];
        const float g5  = (l >= 2  && l <= LL - 3)  ? ws0 : 0.0f;
        const float g10 = (l >= 5  && l <= LL - 5)  ? ws1 : 0.0f;
        const float g20 = (l >= 10 && l <= LL - 10) ? ws2 : 0.0f;
        float o;
        {   // w=5:  cs_arr[l+3] -> pos u+18, cs_arr[l-2] -> pos u+13
            const float mean = (Vx[u + 18] - Vx[u + 13]) * 0.2f;
            const float m2   = (Vy[u + 18] - Vy[u + 13]) * 0.2f;
            const float var  = fmaxf(m2 - mean * mean, 0.0f);
            o = g5 * ((xc - mean) * rsqrtf(var + 1e-5f));
        }
        {   // w=10: pos u+20 / u+10
            const float mean = (Vx[u + 20] - Vx[u + 10]) * 0.1f;
            const float m2   = (Vy[u + 20] - Vy[u + 10]) * 0.1f;
            const float var  = fmaxf(m2 - mean * mean, 0.0f);
            o += g10 * ((xc - mean) * rsqrtf(var + 1e-5f));
        }
        {   // w=20: pos u+25 / u+5
            const float mean = (Vx[u + 25] - Vx[u + 5]) * 0.05f;
            const float m2   = (Vy[u + 25] - Vy[u + 5]) * 0.05f;
            const float var  = fmaxf(m2 - mean * mean, 0.0f);
            o += g20 * ((xc - mean) * rsqrtf(var + 1e-5f));
        }
        ob[(size_t)u * FF] = o;
    }
}

// ---------- fallback: verified single-kernel r6 (if ws too small) ----------
__global__ __launch_bounds__(256) void fan_blocked(const float* __restrict__ x,
                                                   const float* __restrict__ w,
                                                   float* __restrict__ out) {
    __shared__ float2 V[LL];
    __shared__ float2 T0s[NBLK];
    __shared__ float2 T1[NOB];
    __shared__ float2 S2[NOB];
    const int col = blockIdx.x;
    const int f   = col & (FF - 1);
    const int b   = col >> 7;
    const int tid = (int)threadIdx.x;
    const float* xcol = x   + (size_t)b * LL * FF + f;
    float*       ocol = out + (size_t)b * LL * FF + f;
    for (int l = tid; l < LL; l += 256) {
        const float v = sani(xcol[(size_t)l * FF]);
        V[l] = make_float2(v, __fmul_rn(v, v));
    }
    __syncthreads();
    {
        const int bse = tid * BASE;
        float cs = V[bse].x, cs2 = V[bse].y;
        for (int u = 1; u < BASE; ++u) {
            const float2 e = V[bse + u];
            cs = __fadd_rn(cs, e.x); cs2 = __fadd_rn(cs2, e.y);
            V[bse + u] = make_float2(cs, cs2);
        }
        T0s[tid] = make_float2(cs, cs2);
    }
    __syncthreads();
    if (tid < NOB) {
        const int bse = tid * BASE;
        float cs = T0s[bse].x, cs2 = T0s[bse].y;
        for (int u = 1; u < BASE; ++u) {
            const float2 e = T0s[bse + u];
            cs = __fadd_rn(cs, e.x); cs2 = __fadd_rn(cs2, e.y);
            T0s[bse + u] = make_float2(cs, cs2);
        }
        T1[tid] = make_float2(cs, cs2);
    }
    __syncthreads();
    if (tid == 0) {
        float cs = T1[0].x, cs2 = T1[0].y;
        S2[0] = T1[0];
        for (int o = 1; o < NOB; ++o) {
            cs = __fadd_rn(cs, T1[o].x); cs2 = __fadd_rn(cs2, T1[o].y);
            S2[o] = make_float2(cs, cs2);
        }
    }
    __syncthreads();
    {
        const int blk = tid;
        if (blk > 0) {
            const int B = blk - 1, ob2 = B >> 4;
            float2 Pp = T0s[B];
            if (ob2 > 0) {
                const float2 s2 = S2[ob2 - 1];
                Pp = make_float2(__fadd_rn(Pp.x, s2.x), __fadd_rn(Pp.y, s2.y));
            }
            const int bse = blk * BASE;
            for (int u = 0; u < BASE; ++u) {
                const float2 sv = V[bse + u];
                V[bse + u] = make_float2(__fadd_rn(sv.x, Pp.x), __fadd_rn(sv.y, Pp.y));
            }
        }
    }
    __syncthreads();
    const float w0 = w[0], w1 = w[1], w2 = w[2];
    const float mx = fmaxf(w0, fmaxf(w1, w2));
    const float e0 = expf(w0 - mx), e1 = expf(w1 - mx), e2 = expf(w2 - mx);
    const float s  = e0 + e1 + e2;
    const float ws0 = e0 / s, ws1 = e1 / s, ws2 = e2 / s;
    auto PV = [&](int j) -> float2 {
        if (j <= 0) return make_float2(0.0f, 0.0f);
        int idx = j - 1; if (idx > LL - 1) idx = LL - 1;
        return V[idx];
    };
    for (int l = tid; l < LL; l += 256) {
        const float xc = sani(xcol[(size_t)l * FF]);
        const float2 A5 = PV(l + 3), B5 = PV(l - 2);
        const float2 A10 = PV(l + 5), B10 = PV(l - 5);
        const float2 A20 = PV(l + 10), B20 = PV(l - 10);
        const float g5  = (l >= 2  && l <= LL - 3)  ? ws0 : 0.0f;
        const float g10 = (l >= 5  && l <= LL - 5)  ? ws1 : 0.0f;
        const float g20 = (l >= 10 && l <= LL - 10) ? ws2 : 0.0f;
        float o;
        {
            const float mean = (A5.x - B5.x) * 0.2f;
            const float m2   = (A5.y - B5.y) * 0.2f;
            const float var  = fmaxf(m2 - mean * mean, 0.0f);
            o = g5 * ((xc - mean) * rsqrtf(var + 1e-5f));
        }
        {
            const float mean = (A10.x - B10.x) * 0.1f;
            const float m2   = (A10.y - B10.y) * 0.1f;
            const float var  = fmaxf(m2 - mean * mean, 0.0f);
            o += g10 * ((xc - mean) * rsqrtf(var + 1e-5f));
        }
        {
            const float mean = (A20.x - B20.x) * 0.05f;
            const float m2   = (A20.y - B20.y) * 0.05f;
            const float var  = fmaxf(m2 - mean * mean, 0.0f);
            o += g20 * ((xc - mean) * rsqrtf(var + 1e-5f));
        }
        ocol[(size_t)l * FF] = o;
    }
}

extern "C" void kernel_launch(void* const* d_in, const int* in_sizes, int n_in,
                              void* d_out, int out_size, void* d_ws, size_t ws_size,
                              hipStream_t stream) {
    const float* x = (const float*)d_in[0];
    const float* w = (const float*)d_in[1];
    float* out     = (float*)d_out;

    const size_t t0_bytes = (size_t)NB * NBLK * FF * sizeof(float2);   // 8 MiB
    if (ws_size >= 2 * t0_bytes) {                                     // 16 MiB (validated)
        float2* T0 = (float2*)d_ws;                                    // becomes s1 in place
        float2* S2 = (float2*)((char*)d_ws + t0_bytes);                // 0.5 MiB
        k_tiles <<<dim3(128, NB), dim3(256), 0, stream>>>(x, T0);
        k_pref_a<<<dim3(NB * 16), dim3(128), 0, stream>>>(T0);
        k_pref_b<<<dim3(NB),      dim3(128), 0, stream>>>(T0, S2);
        k_win2  <<<dim3(128, NB), dim3(256), 0, stream>>>(x, w, T0, S2, out);
    } else {
        fan_blocked<<<dim3(NB * FF), dim3(256), 0, stream>>>(x, w, out);
    }
}